// Round 10
// baseline (298.440 us; speedup 1.0000x reference)
//
#include <hip/hip_runtime.h>
#include <hip/hip_bf16.h>

typedef __bf16 bf16x8 __attribute__((ext_vector_type(8)));
typedef float f32x4 __attribute__((ext_vector_type(4)));

#define IN_DIM 256
#define NT 8

__device__ __forceinline__ float b2f(unsigned short u) {
  union { unsigned int i; float f; } x; x.i = ((unsigned int)u) << 16; return x.f;
}
__device__ __forceinline__ float lo2f(unsigned int w) {
  union { unsigned int i; float f; } x; x.i = w << 16; return x.f;
}
__device__ __forceinline__ float hi2f(unsigned int w) {
  union { unsigned int i; float f; } x; x.i = w & 0xFFFF0000u; return x.f;
}
__device__ __forceinline__ unsigned short f2b(float f) {
  union { float f; unsigned int i; } u; u.f = f;
  unsigned int r = u.i + 0x7FFF + ((u.i >> 16) & 1);
  return (unsigned short)(r >> 16);
}
__device__ __forceinline__ float lrelu(float x) { return x >= 0.f ? x : 0.2f * x; }
__device__ __forceinline__ float ldf(const void* p, size_t i, int isf32) {
  return isf32 ? ((const float*)p)[i] : b2f(((const unsigned short*)p)[i]);
}

// ---------- dtype detector ----------
__global__ void detect_kernel(const unsigned int* __restrict__ hw, int* __restrict__ flag) {
  int tid = threadIdx.x;
  int bad = 0;
  for (int i = 0; i < 4; i++) {
    unsigned int w = hw[tid * 4 + i];
    unsigned int e = (w & 0x7FFFu) >> 7;
    if (e >= 0xC0u) bad++;
  }
#pragma unroll
  for (int off = 32; off; off >>= 1) bad += __shfl_xor(bad, off);
  if (tid == 0) *flag = (bad > 8) ? 1 : 0;
}

// ---------- fused prep: [0,384) W-transpose; [384,448) fold a2; [448,454) he/aD ----------
__global__ void prep_all_kernel(const void* __restrict__ W1, const void* __restrict__ W2,
                                const void* __restrict__ rW2,
                                const void* __restrict__ al1, const void* __restrict__ ar1,
                                const void* __restrict__ al2, const void* __restrict__ ar2,
                                const void* __restrict__ ee1, const void* __restrict__ Wr1,
                                const void* __restrict__ ae1,
                                const void* __restrict__ ee2, const void* __restrict__ Wr2,
                                const void* __restrict__ ae2,
                                unsigned short* __restrict__ W1t,
                                unsigned short* __restrict__ W2t,
                                float* __restrict__ a2l, float* __restrict__ a2r,
                                float* __restrict__ he1, float* __restrict__ he2,
                                float* __restrict__ alD, float* __restrict__ arD,
                                const int* __restrict__ dflag) {
  int isf32 = *dflag;
  int b = blockIdx.x, tid = threadIdx.x;
  if (b < 384) {
    int j = b, k = tid;
    if (j < 256) {
      int src = (j & 3) * 64 + (j >> 2);          // h*64+d
      W1t[j * 256 + k] = f2b(ldf(W1, (size_t)k * 256 + src, isf32));
    } else {
      int o = j - 256;
      float v = (o < 64) ? ldf(W2, (size_t)k * 64 + o, isf32)
                         : ldf(rW2, (size_t)k * 64 + (o - 64), isf32);
      W2t[o * 256 + k] = f2b(v);
    }
  } else if (b < 448) {
    int k = (b - 384) * 4 + (tid >> 6), d = tid & 63;
    float w2 = ldf(W2, (size_t)k * 64 + d, isf32);
    float l2 = w2 * ldf(al2, d, isf32);
    float r2 = w2 * ldf(ar2, d, isf32);
#pragma unroll
    for (int off = 32; off; off >>= 1) { l2 += __shfl_xor(l2, off); r2 += __shfl_xor(r2, off); }
    if (d == 0) { a2l[k] = l2; a2r[k] = r2; }
  } else {
    int bid = b - 448;
    int t = tid >> 5, d = tid & 31;
    if (bid < 4) {
      int h = bid;
      float s = 0.f;
#pragma unroll
      for (int e = 0; e < 32; e++)
        s += ldf(ee1, t * 32 + e, isf32) * ldf(Wr1, (size_t)(t * 32 + e) * 128 + h * 32 + d, isf32);
      float v = s * ldf(ae1, h * 32 + d, isf32);
#pragma unroll
      for (int off = 16; off; off >>= 1) v += __shfl_xor(v, off);
      if (d == 0) he1[t * 4 + h] = v;
    } else if (bid == 4) {
      float s = 0.f;
#pragma unroll
      for (int e = 0; e < 32; e++)
        s += ldf(ee2, t * 32 + e, isf32) * ldf(Wr2, (size_t)(t * 32 + e) * 32 + d, isf32);
      float v = s * ldf(ae2, d, isf32);
#pragma unroll
      for (int off = 16; off; off >>= 1) v += __shfl_xor(v, off);
      if (d == 0) he2[t] = v;
    } else {
      int j = tid;                       // D-major a vectors
      alD[j] = ldf(al1, (j & 3) * 64 + (j >> 2), isf32);
      arD[j] = ldf(ar1, (j & 3) * 64 + (j >> 2), isf32);
    }
  }
}

// ---------- L1 GEMM, full-J (256) per block, fused nodeatt1 epilogue ----------
__global__ __launch_bounds__(256, 2) void gemm1_fused(
    const void* __restrict__ A, int M,
    const unsigned short* __restrict__ Bt,      // W1t [256][256]
    unsigned short* __restrict__ emb1,
    const float* __restrict__ alD, const float* __restrict__ arD,
    float* __restrict__ hl1, float* __restrict__ hr1,
    const int* __restrict__ dflag) {
  __shared__ unsigned short As[64 * 64];
  __shared__ unsigned short Bs[256 * 64];
  __shared__ float lsum[4][64][4];
  __shared__ float rsum[4][64][4];
  int isf32 = *dflag;
  const int tid = threadIdx.x;
  const int m0 = blockIdx.x * 64;
  const int wv = tid >> 6, lane = tid & 63;
  const int q = lane >> 4, m = lane & 15;
  const int jp = wv * 64;
  f32x4 acc[4][4] = {};
  for (int kc = 0; kc < 256; kc += 64) {
    {
      int row = tid >> 2, qt = tid & 3;
      int gr = m0 + row;
      unsigned short tmp[16];
      if (gr < M) {
        if (isf32) {
          const float* ap = (const float*)A + (size_t)gr * 256 + kc + qt * 16;
          float4 v0 = *(const float4*)ap;
          float4 v1 = *(const float4*)(ap + 4);
          float4 v2 = *(const float4*)(ap + 8);
          float4 v3 = *(const float4*)(ap + 12);
          tmp[0]=f2b(v0.x); tmp[1]=f2b(v0.y); tmp[2]=f2b(v0.z); tmp[3]=f2b(v0.w);
          tmp[4]=f2b(v1.x); tmp[5]=f2b(v1.y); tmp[6]=f2b(v1.z); tmp[7]=f2b(v1.w);
          tmp[8]=f2b(v2.x); tmp[9]=f2b(v2.y); tmp[10]=f2b(v2.z); tmp[11]=f2b(v2.w);
          tmp[12]=f2b(v3.x); tmp[13]=f2b(v3.y); tmp[14]=f2b(v3.z); tmp[15]=f2b(v3.w);
        } else {
          const unsigned short* ap = (const unsigned short*)A + (size_t)gr * 256 + kc + qt * 16;
          *(int4*)tmp = *(const int4*)ap;
          *(int4*)(tmp + 8) = *(const int4*)(ap + 8);
        }
      } else {
        for (int x = 0; x < 16; x++) tmp[x] = 0;
      }
      int g0 = (qt * 2) ^ (row & 7);
      int g1 = (qt * 2 + 1) ^ (row & 7);
      *(int4*)(As + row * 64 + g0 * 8) = *(int4*)tmp;
      *(int4*)(As + row * 64 + g1 * 8) = *(int4*)(tmp + 8);
    }
    {
#pragma unroll
      for (int i = 0; i < 8; i++) {
        int id = tid + i * 256;
        int row = id >> 3, gg = id & 7;
        int4 v = *(const int4*)(Bt + (size_t)row * 256 + kc + gg * 8);
        int pg = gg ^ (row & 7);
        *(int4*)(Bs + row * 64 + pg * 8) = v;
      }
    }
    __syncthreads();
#pragma unroll
    for (int ks = 0; ks < 2; ks++) {
      int gk = ks * 4 + q;
      bf16x8 afr[4];
#pragma unroll
      for (int cm = 0; cm < 4; cm++) {
        int row = cm * 16 + m;
        afr[cm] = *(const bf16x8*)(As + row * 64 + (gk ^ (row & 7)) * 8);
      }
#pragma unroll
      for (int cj = 0; cj < 4; cj++) {
        int jr = jp + cj * 16 + m;
        bf16x8 b = *(const bf16x8*)(Bs + jr * 64 + (gk ^ (jr & 7)) * 8);
#pragma unroll
        for (int cm = 0; cm < 4; cm++)
          acc[cm][cj] = __builtin_amdgcn_mfma_f32_16x16x32_bf16(afr[cm], b, acc[cm][cj], 0, 0, 0);
      }
    }
    __syncthreads();
  }
  float al[4], ar[4];
#pragma unroll
  for (int cj = 0; cj < 4; cj++) {
    al[cj] = alD[jp + cj * 16 + m];
    ar[cj] = arD[jp + cj * 16 + m];
  }
#pragma unroll
  for (int cm = 0; cm < 4; cm++) {
#pragma unroll
    for (int r = 0; r < 4; r++) {
      int lrow = cm * 16 + q * 4 + r;
      int gm = m0 + lrow;
      float lp = 0.f, rp = 0.f;
#pragma unroll
      for (int cj = 0; cj < 4; cj++) {
        float v = acc[cm][cj][r];
        if (gm < M) emb1[(size_t)gm * 256 + jp + cj * 16 + m] = f2b(v);
        lp += v * al[cj]; rp += v * ar[cj];
      }
      lp += __shfl_xor(lp, 4); lp += __shfl_xor(lp, 8);
      rp += __shfl_xor(rp, 4); rp += __shfl_xor(rp, 8);
      if (m < 4) { lsum[wv][lrow][m] = lp; rsum[wv][lrow][m] = rp; }
    }
  }
  __syncthreads();
  {
    int row = tid >> 2, h = tid & 3;
    int gm = m0 + row;
    if (gm < M) {
      float l = lsum[0][row][h] + lsum[1][row][h] + lsum[2][row][h] + lsum[3][row][h];
      float r = rsum[0][row][h] + rsum[1][row][h] + rsum[2][row][h] + rsum[3][row][h];
      hl1[(size_t)gm * 4 + h] = l;
      hr1[(size_t)gm * 4 + h] = r;
    }
  }
}

// ---------- L2 GEMM, full-J (128) per block: emb2 | res(+bias) ----------
__global__ __launch_bounds__(256, 2) void gemm2_fused(
    const unsigned short* __restrict__ A, int M,
    const unsigned short* __restrict__ Bt,      // W2t [128][256]
    unsigned short* __restrict__ emb2, unsigned short* __restrict__ res,
    const void* __restrict__ bias, const int* __restrict__ dflag) {
  __shared__ unsigned short As[64 * 64];
  __shared__ unsigned short Bs[128 * 64];
  int isf32 = *dflag;
  const int tid = threadIdx.x;
  const int m0 = blockIdx.x * 64;
  const int wv = tid >> 6, lane = tid & 63;
  const int q = lane >> 4, m = lane & 15;
  const int jp = (wv & 1) * 64;
  const int mh = (wv >> 1) * 32;
  f32x4 acc[2][4] = {};
  for (int kc = 0; kc < 256; kc += 64) {
    {
      int row = tid >> 2, qt = tid & 3;
      int gr = m0 + row;
      unsigned short tmp[16];
      if (gr < M) {
        const unsigned short* ap = A + (size_t)gr * 256 + kc + qt * 16;
        *(int4*)tmp = *(const int4*)ap;
        *(int4*)(tmp + 8) = *(const int4*)(ap + 8);
      } else {
        for (int x = 0; x < 16; x++) tmp[x] = 0;
      }
      int g0 = (qt * 2) ^ (row & 7);
      int g1 = (qt * 2 + 1) ^ (row & 7);
      *(int4*)(As + row * 64 + g0 * 8) = *(int4*)tmp;
      *(int4*)(As + row * 64 + g1 * 8) = *(int4*)(tmp + 8);
    }
    {
#pragma unroll
      for (int i = 0; i < 4; i++) {
        int id = tid + i * 256;
        int row = id >> 3, gg = id & 7;
        int4 v = *(const int4*)(Bt + (size_t)row * 256 + kc + gg * 8);
        int pg = gg ^ (row & 7);
        *(int4*)(Bs + row * 64 + pg * 8) = v;
      }
    }
    __syncthreads();
#pragma unroll
    for (int ks = 0; ks < 2; ks++) {
      int gk = ks * 4 + q;
      bf16x8 afr[2];
#pragma unroll
      for (int cm = 0; cm < 2; cm++) {
        int row = mh + cm * 16 + m;
        afr[cm] = *(const bf16x8*)(As + row * 64 + (gk ^ (row & 7)) * 8);
      }
#pragma unroll
      for (int cj = 0; cj < 4; cj++) {
        int jr = jp + cj * 16 + m;
        bf16x8 b = *(const bf16x8*)(Bs + jr * 64 + (gk ^ (jr & 7)) * 8);
#pragma unroll
        for (int cm = 0; cm < 2; cm++)
          acc[cm][cj] = __builtin_amdgcn_mfma_f32_16x16x32_bf16(afr[cm], b, acc[cm][cj], 0, 0, 0);
      }
    }
    __syncthreads();
  }
  float bv[4];
#pragma unroll
  for (int cj = 0; cj < 4; cj++)
    bv[cj] = (jp == 64) ? ldf(bias, cj * 16 + m, isf32) : 0.f;
#pragma unroll
  for (int cm = 0; cm < 2; cm++) {
#pragma unroll
    for (int r = 0; r < 4; r++) {
      int gm = m0 + mh + cm * 16 + q * 4 + r;
      if (gm < M) {
#pragma unroll
        for (int cj = 0; cj < 4; cj++) {
          float v = acc[cm][cj][r];
          int gj = cj * 16 + m;
          if (jp == 0) emb2[(size_t)gm * 64 + gj] = f2b(v);
          else res[(size_t)gm * 64 + gj] = f2b(v + bv[cj]);
        }
      }
    }
  }
}

// ---------- CSR by destination ----------
__global__ void count_kernel(const int* __restrict__ col, int* __restrict__ cnt,
                             int E_, int N_) {
  int e = blockIdx.x * 256 + threadIdx.x;
  if (e >= E_) return;
  int c = col[e];
  if ((unsigned)c < (unsigned)N_) atomicAdd(&cnt[c], 1);
}

__global__ void scan1_kernel(const int* __restrict__ cnt, int* __restrict__ ptrb,
                             int* __restrict__ bsum, int n) {
  __shared__ int wsum[4];
  int tid = threadIdx.x, lane = tid & 63, wid = tid >> 6;
  int i = blockIdx.x * 256 + tid;
  int v = (i < n) ? cnt[i] : 0;
  int x = v;
#pragma unroll
  for (int off = 1; off < 64; off <<= 1) {
    int y = __shfl_up(x, off);
    if (lane >= off) x += y;
  }
  if (lane == 63) wsum[wid] = x;
  __syncthreads();
  int woff = 0;
#pragma unroll
  for (int k = 0; k < 4; k++) woff += (k < wid) ? wsum[k] : 0;
  if (i < n) ptrb[i] = x - v + woff;
  if (tid == 255) bsum[blockIdx.x] = woff + x;
}

__global__ void scan2_kernel(int* __restrict__ bsum, int* __restrict__ ptrb,
                             int nb, int n) {
  __shared__ int wsum[4];
  int tid = threadIdx.x, lane = tid & 63, wid = tid >> 6;
  int v = (tid < nb) ? bsum[tid] : 0;
  int x = v;
#pragma unroll
  for (int off = 1; off < 64; off <<= 1) {
    int y = __shfl_up(x, off);
    if (lane >= off) x += y;
  }
  if (lane == 63) wsum[wid] = x;
  __syncthreads();
  int woff = 0;
#pragma unroll
  for (int k = 0; k < 4; k++) woff += (k < wid) ? wsum[k] : 0;
  if (tid < nb) bsum[tid] = x - v + woff;
  if (tid == 255) ptrb[n] = woff + x;
}

__global__ void scan3_kernel(int* __restrict__ ptrb, const int* __restrict__ bsum, int n) {
  int i = blockIdx.x * 256 + threadIdx.x;
  if (i < n) ptrb[i] += bsum[blockIdx.x];
}

__global__ void fill_kernel(const int* __restrict__ col, const int* __restrict__ row,
                            const int* __restrict__ ety, const int* __restrict__ ptrb,
                            int* __restrict__ cnt, int* __restrict__ srcc, int E_, int N_) {
  int e = blockIdx.x * 256 + threadIdx.x;
  if (e >= E_) return;
  int c = col[e];
  if ((unsigned)c >= (unsigned)N_) return;
  int pos = atomicSub(&cnt[c], 1) - 1;
  long long slot = (long long)ptrb[c] + pos;
  if (slot >= 0 && slot < E_) {
    int sr = row[e], t = ety[e];
    srcc[slot] = ((unsigned)sr < (unsigned)N_ && (unsigned)t < (unsigned)NT)
                     ? (sr | (t << 20)) : -1;
  }
}

// ---------- layer-1 aggregation: 2 nodes/wave (32 lanes each), no-max softmax ----------
__global__ __launch_bounds__(256) void agg1_kernel(
    const int* __restrict__ ptrb, const int* __restrict__ srcc,
    const float* __restrict__ hl1, const float* __restrict__ hr1,
    const float* __restrict__ he1,
    const unsigned short* __restrict__ emb1, unsigned short* __restrict__ h1,
    const float* __restrict__ a2l, const float* __restrict__ a2r,
    float* __restrict__ hl2, float* __restrict__ hr2,
    int N_, int E_) {
  __shared__ float4 wds[4][2][32];
  __shared__ int sds[4][2][32];
  int wv = threadIdx.x >> 6, lane = threadIdx.x & 63;
  int g = lane >> 5, sub = lane & 31;
  int node = blockIdx.x * 8 + wv * 2 + g;
  if (node >= N_) return;
  int p0 = ptrb[node], p1 = ptrb[node + 1];
  p0 = max(0, min(p0, E_)); p1 = max(p0, min(p1, E_));
  float4 hrv = *(const float4*)(hr1 + 4 * (size_t)node);
  float s0 = 0.f, s1 = 0.f, s2 = 0.f, s3 = 0.f;
  float acc[8] = {0.f,0.f,0.f,0.f,0.f,0.f,0.f,0.f};
  for (int pb = p0; pb < p1; pb += 32) {
    int mc = p1 - pb; if (mc > 32) mc = 32;
    float4 w = {0.f, 0.f, 0.f, 0.f};
    int src = 0;
    if (sub < mc) {
      int spk = srcc[pb + sub];
      if (spk >= 0) {
        int sr = spk & 0xFFFFF, t = spk >> 20;
        float4 a = *(const float4*)(hl1 + 4 * (size_t)sr);
        float4 gg = *(const float4*)(he1 + 4 * (size_t)t);
        w.x = __expf(lrelu(a.x + hrv.x + gg.x));
        w.y = __expf(lrelu(a.y + hrv.y + gg.y));
        w.z = __expf(lrelu(a.z + hrv.z + gg.z));
        w.w = __expf(lrelu(a.w + hrv.w + gg.w));
        src = sr;
      }
    }
    s0 += w.x; s1 += w.y; s2 += w.z; s3 += w.w;
    wds[wv][g][sub] = w;
    sds[wv][g][sub] = src;
    // per-wave LDS region; in-order wave execution keeps this coherent.
    // all 32 lanes of a group read the same LDS word -> broadcast (free).
    for (int j = 0; j < mc; j += 2) {
      bool v1 = (j + 1) < mc;
      float4 u0 = wds[wv][g][j];
      int r0 = sds[wv][g][j];
      int4 raw0 = *(const int4*)(emb1 + (size_t)r0 * 256 + sub * 8);
      float4 u1; int r1 = 0; int4 raw1;
      if (v1) { u1 = wds[wv][g][j + 1]; r1 = sds[wv][g][j + 1];
                raw1 = *(const int4*)(emb1 + (size_t)r1 * 256 + sub * 8); }
      acc[0] += u0.x * lo2f(raw0.x); acc[1] += u0.y * hi2f(raw0.x);
      acc[2] += u0.z * lo2f(raw0.y); acc[3] += u0.w * hi2f(raw0.y);
      acc[4] += u0.x * lo2f(raw0.z); acc[5] += u0.y * hi2f(raw0.z);
      acc[6] += u0.z * lo2f(raw0.w); acc[7] += u0.w * hi2f(raw0.w);
      if (v1) {
        acc[0] += u1.x * lo2f(raw1.x); acc[1] += u1.y * hi2f(raw1.x);
        acc[2] += u1.z * lo2f(raw1.y); acc[3] += u1.w * hi2f(raw1.y);
        acc[4] += u1.x * lo2f(raw1.z); acc[5] += u1.y * hi2f(raw1.z);
        acc[6] += u1.z * lo2f(raw1.w); acc[7] += u1.w * hi2f(raw1.w);
      }
    }
  }
  // s-reduce within the 32-lane group (xor<32 stays in-group)
#pragma unroll
  for (int off = 1; off < 32; off <<= 1) {
    s0 += __shfl_xor(s0, off); s1 += __shfl_xor(s1, off);
    s2 += __shfl_xor(s2, off); s3 += __shfl_xor(s3, off);
  }
  float sv[4] = {s0, s1, s2, s3};
  unsigned short o[8];
  float lp = 0.f, rp = 0.f;
#pragma unroll
  for (int k = 0; k < 8; k++) {
    float r = (sv[k & 3] > 0.f) ? acc[k] / sv[k & 3] : 0.f;
    r = r > 0.f ? r : __expf(r) - 1.f;       // elu
    o[k] = f2b(r);
    int j = sub * 8 + k;
    lp += r * a2l[j];
    rp += r * a2r[j];
  }
  *(int4*)(h1 + (size_t)node * 256 + sub * 8) = *(int4*)o;
  // fused nodeatt2 partial: reduce within group
#pragma unroll
  for (int off = 1; off < 32; off <<= 1) { lp += __shfl_xor(lp, off); rp += __shfl_xor(rp, off); }
  if (sub == 0) { hl2[node] = lp; hr2[node] = rp; }
}

// ---------- layer-2 aggregation: 4 nodes/wave (16 lanes each) + residual -> d_out ----------
__global__ __launch_bounds__(256) void agg2_kernel(
    const int* __restrict__ ptrb, const int* __restrict__ srcc,
    const float* __restrict__ hl2, const float* __restrict__ hr2,
    const float* __restrict__ he2,
    const unsigned short* __restrict__ emb2, const unsigned short* __restrict__ res,
    void* __restrict__ out, int N_, int E_, const int* __restrict__ dflag) {
  __shared__ int2 wsd[4][4][16];
  int isf32 = *dflag;
  int wv = threadIdx.x >> 6, lane = threadIdx.x & 63;
  int g = lane >> 4, sub = lane & 15;
  int node = blockIdx.x * 16 + wv * 4 + g;
  if (node >= N_) return;
  int p0 = ptrb[node], p1 = ptrb[node + 1];
  p0 = max(0, min(p0, E_)); p1 = max(p0, min(p1, E_));
  float hrv = hr2[node];
  float s = 0.f;
  float acc[4] = {0.f, 0.f, 0.f, 0.f};
  for (int pb = p0; pb < p1; pb += 16) {
    int mc = p1 - pb; if (mc > 16) mc = 16;
    float w = 0.f;
    int src = 0;
    if (sub < mc) {
      int spk = srcc[pb + sub];
      if (spk >= 0) {
        int sr = spk & 0xFFFFF, t = spk >> 20;
        w = __expf(lrelu(hl2[sr] + hrv + he2[t]));
        src = sr;
      }
    }
    s += w;
    int2 pk; pk.x = __float_as_int(w); pk.y = src;
    wsd[wv][g][sub] = pk;
    for (int j = 0; j < mc; j += 2) {
      bool v1 = (j + 1) < mc;
      int2 ws0 = wsd[wv][g][j];
      float u0 = __int_as_float(ws0.x); int r0 = ws0.y;
      int2 raw0 = *(const int2*)(emb2 + (size_t)r0 * 64 + sub * 4);
      float u1; int r1 = 0; int2 raw1;
      if (v1) { int2 ws1 = wsd[wv][g][j + 1];
                u1 = __int_as_float(ws1.x); r1 = ws1.y;
                raw1 = *(const int2*)(emb2 + (size_t)r1 * 64 + sub * 4); }
      acc[0] += u0 * lo2f(raw0.x); acc[1] += u0 * hi2f(raw0.x);
      acc[2] += u0 * lo2f(raw0.y); acc[3] += u0 * hi2f(raw0.y);
      if (v1) {
        acc[0] += u1 * lo2f(raw1.x); acc[1] += u1 * hi2f(raw1.x);
        acc[2] += u1 * lo2f(raw1.y); acc[3] += u1 * hi2f(raw1.y);
      }
    }
  }
  // s-reduce within 16-lane group
#pragma unroll
  for (int off = 1; off < 16; off <<= 1) s += __shfl_xor(s, off);
  ushort4 rv = *(const ushort4*)(res + (size_t)node * 64 + sub * 4);
  float o0 = ((s > 0.f) ? acc[0] / s : 0.f) + b2f(rv.x);
  float o1 = ((s > 0.f) ? acc[1] / s : 0.f) + b2f(rv.y);
  float o2 = ((s > 0.f) ? acc[2] / s : 0.f) + b2f(rv.z);
  float o3 = ((s > 0.f) ? acc[3] / s : 0.f) + b2f(rv.w);
  size_t oi = (size_t)node * 64 + sub * 4;
  if (isf32) {
    float4 ov = {o0, o1, o2, o3};
    *(float4*)((float*)out + oi) = ov;
  } else {
    ushort4 ov; ov.x = f2b(o0); ov.y = f2b(o1); ov.z = f2b(o2); ov.w = f2b(o3);
    *(ushort4*)((unsigned short*)out + oi) = ov;
  }
}

extern "C" void kernel_launch(void* const* d_in, const int* in_sizes, int n_in,
                              void* d_out, int out_size, void* d_ws, size_t ws_size,
                              hipStream_t stream) {
  const int N = in_sizes[0] / IN_DIM;
  const int E = in_sizes[1];

  const void* h   = d_in[0];
  const int* row  = (const int*)d_in[1];
  const int* col  = (const int*)d_in[2];
  const int* ety  = (const int*)d_in[3];
  const void* ee1 = d_in[4];
  const void* W1  = d_in[5];
  const void* Wr1 = d_in[6];
  const void* al1 = d_in[7];
  const void* ar1 = d_in[8];
  const void* ae1 = d_in[9];
  const void* ee2 = d_in[10];
  const void* W2  = d_in[11];
  const void* Wr2 = d_in[12];
  const void* al2 = d_in[13];
  const void* ar2 = d_in[14];
  const void* ae2 = d_in[15];
  const void* rW2 = d_in[16];
  const void* rb2 = d_in[17];

  char* p = (char*)d_ws;
  auto take = [&](size_t b) { char* q = p; p += (b + 255) & ~(size_t)255; return q; };
  unsigned short* h1   = (unsigned short*)take((size_t)N * 256 * 2);   // 25.6 MB
  unsigned short* emb1 = (unsigned short*)take((size_t)N * 256 * 2);   // 25.6 MB (layer2 aliases)
  int* srcc = (int*)take((size_t)E * 4);
  int* ptrb = (int*)take((size_t)(N + 1) * 4);
  int* cnt  = (int*)take((size_t)N * 4);
  int* bsum = (int*)take(1024);
  float* hl1 = (float*)take((size_t)N * 4 * 4);
  float* hr1 = (float*)take((size_t)N * 4 * 4);
  float* hl2 = (float*)take((size_t)N * 4);
  float* hr2 = (float*)take((size_t)N * 4);
  unsigned short* W1t = (unsigned short*)take(256 * 256 * 2);
  unsigned short* W2t = (unsigned short*)take(128 * 256 * 2);
  float* a2l = (float*)take(256 * 4);
  float* a2r = (float*)take(256 * 4);
  float* alD = (float*)take(256 * 4);
  float* arD = (float*)take(256 * 4);
  float* he1 = (float*)take(NT * 4 * 4);
  float* he2 = (float*)take(NT * 4);
  int* dflag = (int*)take(256);
  unsigned short* emb2 = emb1;                     // aliases dead emb1 after agg1
  unsigned short* res  = emb1 + (size_t)N * 64;

  const size_t need = (size_t)(p - (char*)d_ws);
  if (need > ws_size) {
    hipMemsetAsync(d_out, 0, (size_t)out_size * 2, stream);
    return;
  }

  const int EB = (E + 255) / 256;
  const int MB = (N + 63) / 64;
  const int SB = (N + 255) / 256;

  detect_kernel<<<1, 64, 0, stream>>>((const unsigned int*)h, dflag);
  hipMemsetAsync(cnt, 0, (size_t)N * 4, stream);
  prep_all_kernel<<<454, 256, 0, stream>>>(W1, W2, rW2, al1, ar1, al2, ar2,
                                           ee1, Wr1, ae1, ee2, Wr2, ae2,
                                           W1t, W2t, a2l, a2r, he1, he2, alD, arD, dflag);

  // CSR by destination
  count_kernel<<<EB, 256, 0, stream>>>(col, cnt, E, N);
  scan1_kernel<<<SB, 256, 0, stream>>>(cnt, ptrb, bsum, N);
  scan2_kernel<<<1, 256, 0, stream>>>(bsum, ptrb, SB, N);
  scan3_kernel<<<SB, 256, 0, stream>>>(ptrb, bsum, N);
  fill_kernel<<<EB, 256, 0, stream>>>(col, row, ety, ptrb, cnt, srcc, E, N);

  // layer 1 (nodeatt1 fused into gemm; nodeatt2 fused into agg1)
  gemm1_fused<<<MB, 256, 0, stream>>>(h, N, W1t, emb1, alD, arD, hl1, hr1, dflag);
  agg1_kernel<<<(N + 7) / 8, 256, 0, stream>>>(
      ptrb, srcc, hl1, hr1, he1, emb1, h1, a2l, a2r, hl2, hr2, N, E);

  // layer 2
  gemm2_fused<<<MB, 256, 0, stream>>>(h1, N, W2t, emb2, res, rb2, dflag);
  agg2_kernel<<<(N + 15) / 16, 256, 0, stream>>>(
      ptrb, srcc, hl2, hr2, he2, emb2, res, d_out, N, E, dflag);
}